// Round 3
// baseline (554.195 us; speedup 1.0000x reference)
//
#include <hip/hip_runtime.h>
#include <hip/hip_bf16.h>

// ---------------------------------------------------------------------------
// SinkhornLinear: W = sinkhorn(weight) [1024x1024], out = x @ W^T
// x: [8,4096,1024] fp32 -> M=32768, K=1024, N=1024, out fp32.
//
// R8: persistent Sinkhorn. R7 measured ~21us/step x10 (launch-granularity
// floor: device work per step ~3us). R6 measured cg::grid_sync ~108us/barrier
// @1024 blocks -> hand-rolled two-level epoch barrier (16 subs -> root,
// agent-scope atomics, s_sleep backoff, bounded spin) at 256 blocks,
// cooperative launch for co-residency. Multiplicative space (validated R6):
//   u=exp(-0.5C), v=exp(-0.5R), E=exp(8w) in REGISTERS
//   rowsum_i = sum_j E[i][j]*u_j ; colsum_j = sum_i E[i][j]*v_i
//   v' = sqrt(v)*rsqrt(rowsum)   ; u' = sqrt(u)*rsqrt(colsum)
//   W[i][j] = E[i][j]*v_i*u_j -> bf16 (folded into tail; make_w eliminated)
// Fallbacks: coop-launch rejected or ws too small -> R7 multi-dispatch path.
//
// ws layout (persistent path): bar[256 ints, 1KB] | ubuf[2][1024] |
//   vbuf[2][1024] (16KB) | Wb bf16 2MB.  need_p = 1KB+16KB+2MB.
// ---------------------------------------------------------------------------

typedef __attribute__((ext_vector_type(8))) short short8;   // 8 bf16 = 4 VGPRs
typedef __attribute__((ext_vector_type(4))) float f32x4;

// packed fp32x2 -> bf16x2 (hardware cvt_pk, round-to-nearest-even)
__device__ inline unsigned int pk2(float a, float b) {
  __hip_bfloat162 h = __float22bfloat162_rn(make_float2(a, b));
  union { __hip_bfloat162 h; unsigned int u; } cv;
  cv.h = h;
  return cv.u;
}

// Two-level grid barrier, epoch-indexed (no counter reuse -> no reset race).
// bar[it*16 + sub] sub-counters (16 blocks each), bar[160+it] root.
// Bounded spin: a logic bug fails the bench instead of hanging the box.
__device__ __forceinline__ void gbarrier(int* bar, int it) {
  __syncthreads();
  if (threadIdx.x == 0) {
    __threadfence();  // make this block's u/v stores visible device-wide
    int* subc = bar + it * 16 + (blockIdx.x & 15);
    int a = __hip_atomic_fetch_add(subc, 1, __ATOMIC_ACQ_REL, __HIP_MEMORY_SCOPE_AGENT);
    if (a == 15)
      __hip_atomic_fetch_add(bar + 160 + it, 1, __ATOMIC_ACQ_REL, __HIP_MEMORY_SCOPE_AGENT);
    int spins = 0;
    while (__hip_atomic_load(bar + 160 + it, __ATOMIC_ACQUIRE, __HIP_MEMORY_SCOPE_AGENT) < 16) {
      __builtin_amdgcn_s_sleep(8);
      if (++spins > (1 << 22)) break;  // ~bounded: fail, don't hang
    }
    __threadfence();
  }
  __syncthreads();
}

// ---------------------------------------------------------------------------
// Persistent fused Sinkhorn + W materialization. 256 blocks x 256 threads.
// Block k owns rows 4k..4k+3 (full 1024-wide slices in regs, split across
// 4 waves x 64 lanes x 16 elems) and cols 4k..4k+3 (4-col slab, 4 rows per
// thread, 16 regs). 10 iterations, 1 barrier each.
// ---------------------------------------------------------------------------
__global__ __launch_bounds__(256, 1) void sinkhorn_fused(
    const float* __restrict__ w,
    int* __restrict__ bar,
    float* __restrict__ ubuf,          // [2][1024]
    float* __restrict__ vbuf,          // [2][1024]
    unsigned short* __restrict__ Wb) {
  __shared__ float uL[1024];
  __shared__ float vL[1024];
  __shared__ float redC[4][4];
  const int k = blockIdx.x;
  const int t = threadIdx.x;
  const int l = t & 63, wv = t >> 6;
  const int row = 4 * k + wv;

  // E row slice: row, cols l*16 .. l*16+15 (coalesced 64B/lane)
  float er[16];
  {
    const float* rp = w + (size_t)row * 1024 + l * 16;
    #pragma unroll
    for (int q = 0; q < 4; ++q) {
      float4 v4 = *(const float4*)(rp + q * 4);
      er[q * 4 + 0] = __expf(8.f * v4.x);
      er[q * 4 + 1] = __expf(8.f * v4.y);
      er[q * 4 + 2] = __expf(8.f * v4.z);
      er[q * 4 + 3] = __expf(8.f * v4.w);
    }
  }
  // E col slab: rows 4t..4t+3 x cols 4k..4k+3 (16B/row loads; L3 amortizes)
  float ecs[4][4];
  {
    #pragma unroll
    for (int q = 0; q < 4; ++q) {
      float4 v4 = *(const float4*)(w + (size_t)(4 * t + q) * 1024 + 4 * k);
      ecs[q][0] = __expf(8.f * v4.x);
      ecs[q][1] = __expf(8.f * v4.y);
      ecs[q][2] = __expf(8.f * v4.z);
      ecs[q][3] = __expf(8.f * v4.w);
    }
  }

  float vold = 1.f;   // authoritative in lane 0 of each wave (row 4k+wv)
  float uold = 1.f;   // authoritative in wave 0, lanes 0..3 (col 4k+l)

  for (int it = 0; it < 10; ++it) {
    const int rsl = it & 1;          // slot written by previous iter
    const int wsl = (it + 1) & 1;
    float ul[16], vv[4];
    if (it == 0) {
      #pragma unroll
      for (int q = 0; q < 16; ++q) ul[q] = 1.f;
      vv[0] = vv[1] = vv[2] = vv[3] = 1.f;
    } else {
      // stage u (XOR-swizzled 16B chunks: read pattern l*4+q hits 2 banks
      // unswizzled = 32-way conflict) and v (natural chunk=t, conflict-free)
      {
        float4 uu = *(const float4*)(ubuf + rsl * 1024 + t * 4);
        float4 vx = *(const float4*)(vbuf + rsl * 1024 + t * 4);
        int cp = t ^ ((t >> 3) & 7);
        *(float4*)(uL + cp * 4) = uu;
        *(float4*)(vL + t * 4) = vx;
      }
      __syncthreads();
      #pragma unroll
      for (int q = 0; q < 4; ++q) {
        int c = l * 4 + q;
        int cp = c ^ ((c >> 3) & 7);
        float4 u4 = *(const float4*)(uL + cp * 4);
        ul[q * 4 + 0] = u4.x; ul[q * 4 + 1] = u4.y;
        ul[q * 4 + 2] = u4.z; ul[q * 4 + 3] = u4.w;
      }
      float4 v4 = *(const float4*)(vL + t * 4);
      vv[0] = v4.x; vv[1] = v4.y; vv[2] = v4.z; vv[3] = v4.w;
    }

    // row sum: rs = sum_j E[row][j]*u[j]
    float rs = 0.f;
    #pragma unroll
    for (int q = 0; q < 16; ++q) rs += er[q] * ul[q];
    #pragma unroll
    for (int off = 32; off > 0; off >>= 1) rs += __shfl_down(rs, off);

    // col partial sums over this thread's 4 rows
    float cs0 = 0.f, cs1 = 0.f, cs2 = 0.f, cs3 = 0.f;
    #pragma unroll
    for (int q = 0; q < 4; ++q) {
      cs0 += ecs[q][0] * vv[q]; cs1 += ecs[q][1] * vv[q];
      cs2 += ecs[q][2] * vv[q]; cs3 += ecs[q][3] * vv[q];
    }
    #pragma unroll
    for (int off = 32; off > 0; off >>= 1) {
      cs0 += __shfl_down(cs0, off); cs1 += __shfl_down(cs1, off);
      cs2 += __shfl_down(cs2, off); cs3 += __shfl_down(cs3, off);
    }
    if (l == 0) {
      redC[wv][0] = cs0; redC[wv][1] = cs1;
      redC[wv][2] = cs2; redC[wv][3] = cs3;
      // v update for row 4k+wv
      vold = sqrtf(vold) * rsqrtf(rs);
      vbuf[wsl * 1024 + row] = vold;
    }
    __syncthreads();
    if (wv == 0 && l < 4) {
      float tot = redC[0][l] + redC[1][l] + redC[2][l] + redC[3][l];
      uold = sqrtf(uold) * rsqrtf(tot);
      ubuf[wsl * 1024 + 4 * k + l] = uold;
    }
    gbarrier(bar, it);
  }
  // final u,v in slot 0 (iter 9 wrote wsl=0)

  // tail: Wb[row][j] = E[row][j]*v[row]*u[j] -> bf16 (replaces make_w)
  {
    float4 uu = *(const float4*)(ubuf + t * 4);
    int cp = t ^ ((t >> 3) & 7);
    *(float4*)(uL + cp * 4) = uu;
  }
  __syncthreads();
  const float vfin = __shfl(vold, 0);
  unsigned int o[8];
  #pragma unroll
  for (int q = 0; q < 4; ++q) {
    int c = l * 4 + q;
    int cp = c ^ ((c >> 3) & 7);
    float4 u4 = *(const float4*)(uL + cp * 4);
    float p0 = er[q * 4 + 0] * vfin * u4.x;
    float p1 = er[q * 4 + 1] * vfin * u4.y;
    float p2 = er[q * 4 + 2] * vfin * u4.z;
    float p3 = er[q * 4 + 3] * vfin * u4.w;
    o[q * 2 + 0] = pk2(p0, p1);
    o[q * 2 + 1] = pk2(p2, p3);
  }
  unsigned short* wp = Wb + (size_t)row * 1024 + l * 16;
  *(uint4*)(wp) = *(uint4*)(o);
  *(uint4*)(wp + 8) = *(uint4*)(o + 4);
}

// ---------------------------------------------------------------------------
// Fallback path (R7, verified 394us): per-step kernel + make_w.
// ---------------------------------------------------------------------------
__global__ void sinkhorn_step(const float* __restrict__ w,
                              const float* __restrict__ Rin,
                              const float* __restrict__ Cin,
                              float* __restrict__ Rout,
                              float* __restrict__ Cout,
                              int first) {
  __shared__ float red[4];
  const int tid = threadIdx.x;
  const int b = blockIdx.x;
  const int lane = tid & 63, wv = tid >> 6;
  if (b < 1024) {
    const int j = tid * 4;
    float4 v = *(const float4*)(w + (size_t)b * 1024 + j);
    float4 cv = make_float4(0.f, 0.f, 0.f, 0.f);
    if (!first) cv = *(const float4*)(Cin + j);
    float s = __expf(8.f * v.x - 0.5f * cv.x) + __expf(8.f * v.y - 0.5f * cv.y)
            + __expf(8.f * v.z - 0.5f * cv.z) + __expf(8.f * v.w - 0.5f * cv.w);
    #pragma unroll
    for (int off = 32; off > 0; off >>= 1) s += __shfl_down(s, off);
    if (lane == 0) red[wv] = s;
    __syncthreads();
    if (tid == 0) {
      float t = red[0] + red[1] + red[2] + red[3];
      Rout[b] = (first ? 0.f : 0.5f * Rin[b]) + __logf(t);
    }
  } else {
    const int c = b - 1024;
    const int j = ((c & 7) << 7) + (c >> 3);
    const int i0 = tid * 4;
    const float* wp = w + (size_t)i0 * 1024 + j;
    float4 rv = make_float4(0.f, 0.f, 0.f, 0.f);
    if (!first) rv = *(const float4*)(Rin + i0);
    float s = __expf(8.f * wp[0]    - 0.5f * rv.x)
            + __expf(8.f * wp[1024] - 0.5f * rv.y)
            + __expf(8.f * wp[2048] - 0.5f * rv.z)
            + __expf(8.f * wp[3072] - 0.5f * rv.w);
    #pragma unroll
    for (int off = 32; off > 0; off >>= 1) s += __shfl_down(s, off);
    if (lane == 0) red[wv] = s;
    __syncthreads();
    if (tid == 0) {
      float t = red[0] + red[1] + red[2] + red[3];
      Cout[j] = (first ? 0.f : 0.5f * Cin[j]) + __logf(t);
    }
  }
}

__global__ void make_w(const float* __restrict__ w, const float* __restrict__ R,
                       const float* __restrict__ C, unsigned short* __restrict__ Wb) {
  const int i = blockIdx.x;
  const int j = threadIdx.x * 4;
  const float r = 0.5f * R[i];
  float4 v = *(const float4*)(w + (size_t)i * 1024 + j);
  float4 cv = *(const float4*)(C + j);
  unsigned int o[2];
  o[0] = pk2(__expf(8.f * v.x - r - 0.5f * cv.x), __expf(8.f * v.y - r - 0.5f * cv.y));
  o[1] = pk2(__expf(8.f * v.z - r - 0.5f * cv.z), __expf(8.f * v.w - r - 0.5f * cv.w));
  *(uint2*)(Wb + (size_t)i * 1024 + j) = *(uint2*)o;
}

// XCD-group swizzle: id = h*64 + n*8 + c  ->  m-slab = c + 8h, n-slab = n.
__device__ inline void swizzle_mn(int id, int& m0, int& n0) {
  m0 = ((id & 7) + ((id >> 6) << 3)) << 7;
  n0 = ((id >> 3) & 7) << 7;
}

// ---------------------------------------------------------------------------
// Path A GEMM: Wb bf16 materialized; B via global_load_lds width-16,
// A fp32 -> packed bf16 cvt -> ds_write. 128x128 tile, BK=32, 4 waves 2x2.
// ---------------------------------------------------------------------------
__global__ __launch_bounds__(256) void gemm_a(const float* __restrict__ X,
                                              const unsigned short* __restrict__ Wb,
                                              float* __restrict__ out) {
  __shared__ unsigned short As[128 * 32];
  __shared__ unsigned short Bs[128 * 32];
  const int tid = threadIdx.x;
  const int lane = tid & 63, wave = tid >> 6;
  const int wm = wave >> 1, wn = wave & 1;
  int m0, n0;
  swizzle_mn(blockIdx.x, m0, n0);

  f32x4 acc[4][4] = {};
  const int sr = tid >> 1, sk = (tid & 1) * 16;
  const float* Xrow = X + (size_t)(m0 + sr) * 1024 + sk;

  for (int k0 = 0; k0 < 1024; k0 += 32) {
    #pragma unroll
    for (int is = 0; is < 2; ++is) {
      int idx = is * 256 + tid;
      const unsigned short* g = Wb + (size_t)(n0 + (idx >> 2)) * 1024 + k0 + (idx & 3) * 8;
      unsigned short* l = Bs + (is * 256 + wave * 64) * 8;  // wave-uniform base
      __builtin_amdgcn_global_load_lds(
          (const __attribute__((address_space(1))) unsigned int*)g,
          (__attribute__((address_space(3))) unsigned int*)l, 16, 0, 0);
    }
    float4 va0 = *(const float4*)(Xrow + k0);
    float4 va1 = *(const float4*)(Xrow + k0 + 4);
    float4 va2 = *(const float4*)(Xrow + k0 + 8);
    float4 va3 = *(const float4*)(Xrow + k0 + 12);
    unsigned int pk[8];
    pk[0] = pk2(va0.x, va0.y); pk[1] = pk2(va0.z, va0.w);
    pk[2] = pk2(va1.x, va1.y); pk[3] = pk2(va1.z, va1.w);
    pk[4] = pk2(va2.x, va2.y); pk[5] = pk2(va2.z, va2.w);
    pk[6] = pk2(va3.x, va3.y); pk[7] = pk2(va3.z, va3.w);
    *(uint4*)(As + sr * 32 + sk)     = *(uint4*)(pk);
    *(uint4*)(As + sr * 32 + sk + 8) = *(uint4*)(pk + 4);

    __syncthreads();

    const int kq = (lane >> 4) * 8;
    const int fr = lane & 15;
    short8 af[4], bf[4];
    #pragma unroll
    for (int t = 0; t < 4; ++t)
      af[t] = *(const short8*)(As + (wm * 64 + t * 16 + fr) * 32 + kq);
    #pragma unroll
    for (int t = 0; t < 4; ++t)
      bf[t] = *(const short8*)(Bs + (wn * 64 + t * 16 + fr) * 32 + kq);
    #pragma unroll
    for (int mt = 0; mt < 4; ++mt)
      #pragma unroll
      for (int nt = 0; nt < 4; ++nt)
        acc[mt][nt] = __builtin_amdgcn_mfma_f32_16x16x32_bf16(af[mt], bf[nt], acc[mt][nt], 0, 0, 0);

    __syncthreads();
  }

  const int crow0 = m0 + wm * 64 + (lane >> 4) * 4;
  const int ccol0 = n0 + wn * 64 + (lane & 15);
  #pragma unroll
  for (int mt = 0; mt < 4; ++mt)
    #pragma unroll
    for (int nt = 0; nt < 4; ++nt)
      #pragma unroll
      for (int r = 0; r < 4; ++r)
        out[(size_t)(crow0 + mt * 16 + r) * 1024 + ccol0 + nt * 16] = acc[mt][nt][r];
}

// ---------------------------------------------------------------------------
// Path B GEMM (fallback, small ws): W recomputed in B-staging.
// ---------------------------------------------------------------------------
__global__ __launch_bounds__(256) void gemm_b(const float* __restrict__ X,
                                              const float* __restrict__ w,
                                              const float* __restrict__ R,
                                              const float* __restrict__ C,
                                              float* __restrict__ out) {
  __shared__ unsigned short As[128 * 32];
  __shared__ unsigned short Bs[128 * 32];
  const int tid = threadIdx.x;
  const int lane = tid & 63, wave = tid >> 6;
  const int wm = wave >> 1, wn = wave & 1;
  int m0, n0;
  swizzle_mn(blockIdx.x, m0, n0);

  f32x4 acc[4][4] = {};
  const int sr = tid >> 1, sk = (tid & 1) * 16;
  const float* Xrow = X + (size_t)(m0 + sr) * 1024 + sk;
  const float* Wrow = w + (size_t)(n0 + sr) * 1024 + sk;
  const float rpot = 0.5f * R[n0 + sr];

  for (int k0 = 0; k0 < 1024; k0 += 32) {
    float4 vb0 = *(const float4*)(Wrow + k0);
    float4 vb1 = *(const float4*)(Wrow + k0 + 4);
    float4 vb2 = *(const float4*)(Wrow + k0 + 8);
    float4 vb3 = *(const float4*)(Wrow + k0 + 12);
    float4 vc0 = *(const float4*)(C + k0 + sk);
    float4 vc1 = *(const float4*)(C + k0 + sk + 4);
    float4 vc2 = *(const float4*)(C + k0 + sk + 8);
    float4 vc3 = *(const float4*)(C + k0 + sk + 12);
    unsigned int pb[8];
    pb[0] = pk2(__expf(8.f * vb0.x - rpot - 0.5f * vc0.x), __expf(8.f * vb0.y - rpot - 0.5f * vc0.y));
    pb[1] = pk2(__expf(8.f * vb0.z - rpot - 0.5f * vc0.z), __expf(8.f * vb0.w - rpot - 0.5f * vc0.w));
    pb[2] = pk2(__expf(8.f * vb1.x - rpot - 0.5f * vc1.x), __expf(8.f * vb1.y - rpot - 0.5f * vc1.y));
    pb[3] = pk2(__expf(8.f * vb1.z - rpot - 0.5f * vc1.z), __expf(8.f * vb1.w - rpot - 0.5f * vc1.w));
    pb[4] = pk2(__expf(8.f * vb2.x - rpot - 0.5f * vc2.x), __expf(8.f * vb2.y - rpot - 0.5f * vc2.y));
    pb[5] = pk2(__expf(8.f * vb2.z - rpot - 0.5f * vc2.z), __expf(8.f * vb2.w - rpot - 0.5f * vc2.w));
    pb[6] = pk2(__expf(8.f * vb3.x - rpot - 0.5f * vc3.x), __expf(8.f * vb3.y - rpot - 0.5f * vc3.y));
    pb[7] = pk2(__expf(8.f * vb3.z - rpot - 0.5f * vc3.z), __expf(8.f * vb3.w - rpot - 0.5f * vc3.w));
    float4 va0 = *(const float4*)(Xrow + k0);
    float4 va1 = *(const float4*)(Xrow + k0 + 4);
    float4 va2 = *(const float4*)(Xrow + k0 + 8);
    float4 va3 = *(const float4*)(Xrow + k0 + 12);
    unsigned int pa[8];
    pa[0] = pk2(va0.x, va0.y); pa[1] = pk2(va0.z, va0.w);
    pa[2] = pk2(va1.x, va1.y); pa[3] = pk2(va1.z, va1.w);
    pa[4] = pk2(va2.x, va2.y); pa[5] = pk2(va2.z, va2.w);
    pa[6] = pk2(va3.x, va3.y); pa[7] = pk2(va3.z, va3.w);

    *(uint4*)(Bs + sr * 32 + sk)     = *(uint4*)(pb);
    *(uint4*)(Bs + sr * 32 + sk + 8) = *(uint4*)(pb + 4);
    *(uint4*)(As + sr * 32 + sk)     = *(uint4*)(pa);
    *(uint4*)(As + sr * 32 + sk + 8) = *(uint4*)(pa + 4);

    __syncthreads();

    const int kq = (lane >> 4) * 8;
    const int fr = lane & 15;
    short8 af[4], bf[4];
    #pragma unroll
    for (int t = 0; t < 4; ++t)
      af[t] = *(const short8*)(As + (wm * 64 + t * 16 + fr) * 32 + kq);
    #pragma unroll
    for (int t = 0; t < 4; ++t)
      bf[t] = *(const short8*)(Bs + (wn * 64 + t * 16 + fr) * 32 + kq);
    #pragma unroll
    for (int mt = 0; mt < 4; ++mt)
      #pragma unroll
      for (int nt = 0; nt < 4; ++nt)
        acc[mt][nt] = __builtin_amdgcn_mfma_f32_16x16x32_bf16(af[mt], bf[nt], acc[mt][nt], 0, 0, 0);

    __syncthreads();
  }

  const int crow0 = m0 + wm * 64 + (lane >> 4) * 4;
  const int ccol0 = n0 + wn * 64 + (lane & 15);
  #pragma unroll
  for (int mt = 0; mt < 4; ++mt)
    #pragma unroll
    for (int nt = 0; nt < 4; ++nt)
      #pragma unroll
      for (int r = 0; r < 4; ++r)
        out[(size_t)(crow0 + mt * 16 + r) * 1024 + ccol0 + nt * 16] = acc[mt][nt][r];
}

extern "C" void kernel_launch(void* const* d_in, const int* in_sizes, int n_in,
                              void* d_out, int out_size, void* d_ws, size_t ws_size,
                              hipStream_t stream) {
  const float* x = (const float*)d_in[0];        // [8,4096,1024] fp32
  const float* weight = (const float*)d_in[1];   // [1024,1024] fp32
  float* out = (float*)d_out;                    // [8,4096,1024] fp32

  // persistent-path layout: bar 1KB | ubuf 8KB | vbuf 8KB | Wb 2MB
  int* bar = (int*)d_ws;
  float* ubuf = (float*)d_ws + 256;
  float* vbuf = ubuf + 2048;
  unsigned short* WbP = (unsigned short*)(vbuf + 2048);
  const size_t need_p = 1024 + 16 * 1024 + 2 * 1024 * 1024;

  if (ws_size >= need_p) {
    hipError_t e0 = hipMemsetAsync(bar, 0, 1024, stream);
    if (e0 == hipSuccess) {
      const float* warg = weight;
      int* barArg = bar;
      float* uArg = ubuf; float* vArg = vbuf;
      unsigned short* WbArg = WbP;
      void* args[5] = {(void*)&warg, (void*)&barArg, (void*)&uArg,
                       (void*)&vArg, (void*)&WbArg};
      hipError_t ce = hipLaunchCooperativeKernel((const void*)sinkhorn_fused,
                                                 dim3(256), dim3(256), args, 0,
                                                 stream);
      if (ce == hipSuccess) {
        gemm_a<<<2048, 256, 0, stream>>>(x, WbP, out);
        return;
      }
      (void)hipGetLastError();
    } else {
      (void)hipGetLastError();
    }
  }

  // --- fallback: R7 multi-dispatch path (verified 394us) ---
  float* R0 = (float*)d_ws;
  float* C0 = R0 + 1024;
  float* R1 = C0 + 1024;
  float* C1 = R1 + 1024;
  unsigned short* Wb2 = (unsigned short*)(C1 + 1024);
  const size_t need_a = 16 * 1024 + 2 * 1024 * 1024;

  for (int t = 0; t < 10; ++t) {
    const float *Ri, *Ci;
    float *Ro, *Co;
    if ((t & 1) == 0) { Ri = R0; Ci = C0; Ro = R1; Co = C1; }
    else              { Ri = R1; Ci = C1; Ro = R0; Co = C0; }
    sinkhorn_step<<<2048, 256, 0, stream>>>(weight, Ri, Ci, Ro, Co, (t == 0) ? 1 : 0);
  }
  if (ws_size >= need_a) {
    make_w<<<1024, 256, 0, stream>>>(weight, R0, C0, Wb2);
    gemm_a<<<2048, 256, 0, stream>>>(x, Wb2, out);
  } else {
    gemm_b<<<2048, 256, 0, stream>>>(x, weight, R0, C0, out);
  }
}

// Round 4
// 422.703 us; speedup vs baseline: 1.3111x; 1.3111x over previous
//
#include <hip/hip_runtime.h>
#include <hip/hip_bf16.h>

// ---------------------------------------------------------------------------
// SinkhornLinear: W = sinkhorn(weight) [1024x1024], out = x @ W^T
// x: [8,4096,1024] fp32 -> M=32768, K=1024, N=1024, out fp32.
//
// Measured session facts:
//   - grid-wide sync ~20us/barrier regardless of mechanism (R6 cg: 108us,
//     R8 hand-rolled atomic barrier: 21us) -> persistent Sinkhorn is DEAD.
//   - R7 multi-dispatch path: 394us = ~214 Sinkhorn + ~5 make_w + 175 gemm.
//   - gemm_a counters: MfmaUtil 16%, VALUBusy 35%, LDS conflicts 12.6M
//     (8-way: [128][32]bf16 tile read column-wise), ~49% stall.
//
// R9: (a) gemm_a rebuilt: BK=64, B double-buffered via global_load_lds with
//     counted vmcnt(4) across raw s_barriers (in-flight prefetch, never
//     drain-0 mid-loop), A-loads issued early / written late (T14), both-side
//     XOR chunk swizzle (chunk ^= row&7; A via swizzled ds_write, B via
//     pre-swizzled GLOBAL source + linear LDS dest -> same involution on
//     read). (b) Sinkhorn col part coalesced: 64 blocks x 16 cols, float4
//     row segments.
// ---------------------------------------------------------------------------

typedef __attribute__((ext_vector_type(8))) short short8;   // 8 bf16 = 4 VGPRs
typedef __attribute__((ext_vector_type(4))) float f32x4;

// packed fp32x2 -> bf16x2 (hardware cvt_pk, round-to-nearest-even)
__device__ inline unsigned int pk2(float a, float b) {
  __hip_bfloat162 h = __float22bfloat162_rn(make_float2(a, b));
  union { __hip_bfloat162 h; unsigned int u; } cv;
  cv.h = h;
  return cv.u;
}

// One Sinkhorn iteration. Blocks 0..1023: row lse for row b.
// Blocks 1024..1087: col lse for a 16-column slab (coalesced float4 reads).
__global__ void sinkhorn_step(const float* __restrict__ w,
                              const float* __restrict__ Rin,
                              const float* __restrict__ Cin,
                              float* __restrict__ Rout,
                              float* __restrict__ Cout,
                              int first) {
  __shared__ float red[4];
  __shared__ float4 red4[256];
  const int tid = threadIdx.x;
  const int b = blockIdx.x;
  const int lane = tid & 63, wv = tid >> 6;
  if (b < 1024) {
    // --- row part: sum_j exp(8*w[b][j] - 0.5*C[j]) ---
    const int j = tid * 4;
    float4 v = *(const float4*)(w + (size_t)b * 1024 + j);
    float4 cv = make_float4(0.f, 0.f, 0.f, 0.f);
    if (!first) cv = *(const float4*)(Cin + j);
    float s = __expf(8.f * v.x - 0.5f * cv.x) + __expf(8.f * v.y - 0.5f * cv.y)
            + __expf(8.f * v.z - 0.5f * cv.z) + __expf(8.f * v.w - 0.5f * cv.w);
    #pragma unroll
    for (int off = 32; off > 0; off >>= 1) s += __shfl_down(s, off);
    if (lane == 0) red[wv] = s;
    __syncthreads();
    if (tid == 0) {
      float t = red[0] + red[1] + red[2] + red[3];
      Rout[b] = (first ? 0.f : 0.5f * Rin[b]) + __logf(t);
    }
  } else {
    // --- col part: 16 cols per block; thread t: rows (t>>2)+64p, colchunk t&3.
    // 4 consecutive threads read 64 contiguous bytes of one row -> 16
    // line-segments per wave-instruction (vs 64 uncoalesced before).
    const int cb = b - 1024;
    const int c0 = cb * 16;
    const int rowg = tid >> 2, cg = tid & 3;
    const float* wp = w + (size_t)rowg * 1024 + c0 + cg * 4;
    float ax = 0.f, ay = 0.f, az = 0.f, aw = 0.f;
    #pragma unroll 4
    for (int p = 0; p < 16; ++p) {
      float4 wv4 = *(const float4*)(wp + (size_t)p * 64 * 1024);
      float rp = first ? 0.f : Rin[rowg + p * 64];
      float h = 0.5f * rp;
      ax += __expf(8.f * wv4.x - h);
      ay += __expf(8.f * wv4.y - h);
      az += __expf(8.f * wv4.z - h);
      aw += __expf(8.f * wv4.w - h);
    }
    red4[tid] = make_float4(ax, ay, az, aw);
    __syncthreads();
    if (tid < 16) {
      const int g = tid >> 2, e = tid & 3;
      float s = 0.f;
      #pragma unroll 8
      for (int q = 0; q < 64; ++q)
        s += ((const float*)&red4[q * 4 + g])[e];
      const int col = c0 + tid;
      Cout[col] = (first ? 0.f : 0.5f * Cin[col]) + __logf(s);
    }
  }
}

// W[i][j] = exp(8*w - 0.5*(R[i]+C[j])) -> bf16 (only used when ws allows).
__global__ void make_w(const float* __restrict__ w, const float* __restrict__ R,
                       const float* __restrict__ C, unsigned short* __restrict__ Wb) {
  const int i = blockIdx.x;
  const int j = threadIdx.x * 4;
  const float r = 0.5f * R[i];
  float4 v = *(const float4*)(w + (size_t)i * 1024 + j);
  float4 cv = *(const float4*)(C + j);
  unsigned int o[2];
  o[0] = pk2(__expf(8.f * v.x - r - 0.5f * cv.x), __expf(8.f * v.y - r - 0.5f * cv.y));
  o[1] = pk2(__expf(8.f * v.z - r - 0.5f * cv.z), __expf(8.f * v.w - r - 0.5f * cv.w));
  *(uint2*)(Wb + (size_t)i * 1024 + j) = *(uint2*)o;
}

// XCD-group swizzle: id = h*64 + n*8 + c  ->  m-slab = c + 8h, n-slab = n.
__device__ inline void swizzle_mn(int id, int& m0, int& n0) {
  m0 = ((id & 7) + ((id >> 6) << 3)) << 7;
  n0 = ((id >> 3) & 7) << 7;
}

// ---------------------------------------------------------------------------
// Path A GEMM: 128x128 tile, BK=64, 4 waves 2x2, 16x16x32 bf16 MFMA.
// LDS: As[128][64] (16KB, XOR-swizzled 16B chunks) + Bs[2][128][64] (dbuf).
// B: global_load_lds w16, source pre-swizzled (chunk g = c ^ (row&7)), LDS
//    linear; read applies the same XOR -> conflict-free ds_read_b128.
// Pipeline per K-step: {ds_read frags | issue A(t+1) loads} -> MFMA ->
//   barrier -> cvt+ds_write A(t+1) -> issue B(t+2) gload_lds -> vmcnt(4)
//   (B(t+1) landed; B(t+2) stays in flight) -> barrier.
// ---------------------------------------------------------------------------
__global__ __launch_bounds__(256) void gemm_a(const float* __restrict__ X,
                                              const unsigned short* __restrict__ Wb,
                                              float* __restrict__ out) {
  __shared__ unsigned short As[128 * 64];
  __shared__ unsigned short Bs[2][128 * 64];
  const int tid = threadIdx.x;
  const int lane = tid & 63, wave = tid >> 6;
  const int wm = wave >> 1, wn = wave & 1;
  int m0, n0;
  swizzle_mn(blockIdx.x, m0, n0);

  f32x4 acc[4][4] = {};
  // A staging: thread -> row=tid>>1, k-half=(tid&1)*32 (128B fp32, coalesced)
  const int ar = tid >> 1, ah = tid & 1;
  const float* Xrow = X + (size_t)(m0 + ar) * 1024 + ah * 32;
  const int fr = lane & 15, kq = lane >> 4;   // frag row / k-chunk within 32

  float4 vx[8];

  // --- helpers (macros keep literal args for global_load_lds) ---
#define ISSUE_B(buf, k0)                                                       \
  {                                                                            \
    _Pragma("unroll")                                                          \
    for (int is = 0; is < 4; ++is) {                                           \
      int idx = is * 256 + tid;                                                \
      int lrow = idx >> 3, lc = idx & 7;                                       \
      int g = lc ^ (lrow & 7);                                                 \
      const unsigned short* gp = Wb + (size_t)(n0 + lrow) * 1024 + (k0) + g * 8;\
      unsigned short* l = Bs[buf] + (size_t)(is * 256 + wave * 64) * 8;        \
      __builtin_amdgcn_global_load_lds(                                        \
          (const __attribute__((address_space(1))) unsigned int*)gp,           \
          (__attribute__((address_space(3))) unsigned int*)l, 16, 0, 0);       \
    }                                                                          \
  }

#define LOAD_A(k0)                                                             \
  {                                                                            \
    _Pragma("unroll")                                                          \
    for (int q = 0; q < 8; ++q) vx[q] = *(const float4*)(Xrow + (k0) + q * 4); \
  }

#define WRITE_A()                                                              \
  {                                                                            \
    _Pragma("unroll")                                                          \
    for (int q = 0; q < 4; ++q) {                                              \
      unsigned int o0 = pk2(vx[2 * q].x, vx[2 * q].y);                         \
      unsigned int o1 = pk2(vx[2 * q].z, vx[2 * q].w);                         \
      unsigned int o2 = pk2(vx[2 * q + 1].x, vx[2 * q + 1].y);                 \
      unsigned int o3 = pk2(vx[2 * q + 1].z, vx[2 * q + 1].w);                 \
      int c = ah * 4 + q;                                                      \
      int cp = c ^ (ar & 7);                                                   \
      *(uint4*)(As + (size_t)ar * 64 + cp * 8) = make_uint4(o0, o1, o2, o3);   \
    }                                                                          \
  }

  // --- prologue: stage tile 0, prefetch B tile 1 ---
  ISSUE_B(0, 0);
  LOAD_A(0);
  WRITE_A();              // compiler inserts vmcnt wait for vx
  ISSUE_B(1, 64);
  asm volatile("s_waitcnt vmcnt(4)" ::: "memory");   // B(0) landed
  asm volatile("s_waitcnt lgkmcnt(0)" ::: "memory"); // As writes done
  __builtin_amdgcn_s_barrier();
  __builtin_amdgcn_sched_barrier(0);

  int cur = 0;
  for (int t = 0; t < 16; ++t) {
    const int k0n = (t + 1) * 64;
    if (t < 15) LOAD_A(k0n);           // A(t+1) in flight under MFMA

    #pragma unroll
    for (int kk = 0; kk < 2; ++kk) {
      short8 af[4], bf[4];
      #pragma unroll
      for (int mt = 0; mt < 4; ++mt) {
        int row = wm * 64 + mt * 16 + fr;
        int cp = (kk * 4 + kq) ^ (row & 7);
        af[mt] = *(const short8*)(As + (size_t)row * 64 + cp * 8);
      }
      #pragma unroll
      for (int nt = 0; nt < 4; ++nt) {
        int row = wn * 64 + nt * 16 + fr;
        int cp = (kk * 4 + kq) ^ (row & 7);
        bf[nt] = *(const short8*)(Bs[cur] + (size_t)row * 64 + cp * 8);
      }
      #pragma unroll
      for (int mt = 0; mt < 4; ++mt)
        #pragma unroll
        for (int nt = 0; nt < 4; ++nt)
          acc[mt][nt] = __builtin_amdgcn_mfma_f32_16x16x32_bf16(af[mt], bf[nt], acc[mt][nt], 0, 0, 0);
    }
    if (t == 15) break;

    asm volatile("s_waitcnt lgkmcnt(0)" ::: "memory");
    __builtin_amdgcn_s_barrier();      // all waves done reading As / Bs[cur]
    __builtin_amdgcn_sched_barrier(0);

    WRITE_A();                          // A(t+1) -> As (vmcnt wait by compiler)
    if (t < 14) {
      ISSUE_B(cur, k0n + 64);           // B(t+2) -> freed buffer
      asm volatile("s_waitcnt vmcnt(4)" ::: "memory");  // B(t+1) landed
    } else {
      asm volatile("s_waitcnt vmcnt(0)" ::: "memory");  // tail: B(15) landed
    }
    asm volatile("s_waitcnt lgkmcnt(0)" ::: "memory");
    __builtin_amdgcn_s_barrier();
    __builtin_amdgcn_sched_barrier(0);
    cur ^= 1;
  }

  const int crow0 = m0 + wm * 64 + (lane >> 4) * 4;
  const int ccol0 = n0 + wn * 64 + fr;
  #pragma unroll
  for (int mt = 0; mt < 4; ++mt)
    #pragma unroll
    for (int nt = 0; nt < 4; ++nt)
      #pragma unroll
      for (int r = 0; r < 4; ++r)
        out[(size_t)(crow0 + mt * 16 + r) * 1024 + ccol0 + nt * 16] = acc[mt][nt][r];
#undef ISSUE_B
#undef LOAD_A
#undef WRITE_A
}

// ---------------------------------------------------------------------------
// Path B GEMM (fallback, small ws): W recomputed in B-staging (verified R4
// structure, BK=32, unchanged).
// ---------------------------------------------------------------------------
__global__ __launch_bounds__(256) void gemm_b(const float* __restrict__ X,
                                              const float* __restrict__ w,
                                              const float* __restrict__ R,
                                              const float* __restrict__ C,
                                              float* __restrict__ out) {
  __shared__ unsigned short As[128 * 32];
  __shared__ unsigned short Bs[128 * 32];
  const int tid = threadIdx.x;
  const int lane = tid & 63, wave = tid >> 6;
  const int wm = wave >> 1, wn = wave & 1;
  int m0, n0;
  swizzle_mn(blockIdx.x, m0, n0);

  f32x4 acc[4][4] = {};
  const int sr = tid >> 1, sk = (tid & 1) * 16;
  const float* Xrow = X + (size_t)(m0 + sr) * 1024 + sk;
  const float* Wrow = w + (size_t)(n0 + sr) * 1024 + sk;
  const float rpot = 0.5f * R[n0 + sr];

  for (int k0 = 0; k0 < 1024; k0 += 32) {
    float4 vb0 = *(const float4*)(Wrow + k0);
    float4 vb1 = *(const float4*)(Wrow + k0 + 4);
    float4 vb2 = *(const float4*)(Wrow + k0 + 8);
    float4 vb3 = *(const float4*)(Wrow + k0 + 12);
    float4 vc0 = *(const float4*)(C + k0 + sk);
    float4 vc1 = *(const float4*)(C + k0 + sk + 4);
    float4 vc2 = *(const float4*)(C + k0 + sk + 8);
    float4 vc3 = *(const float4*)(C + k0 + sk + 12);
    unsigned int pb[8];
    pb[0] = pk2(__expf(8.f * vb0.x - rpot - 0.5f * vc0.x), __expf(8.f * vb0.y - rpot - 0.5f * vc0.y));
    pb[1] = pk2(__expf(8.f * vb0.z - rpot - 0.5f * vc0.z), __expf(8.f * vb0.w - rpot - 0.5f * vc0.w));
    pb[2] = pk2(__expf(8.f * vb1.x - rpot - 0.5f * vc1.x), __expf(8.f * vb1.y - rpot - 0.5f * vc1.y));
    pb[3] = pk2(__expf(8.f * vb1.z - rpot - 0.5f * vc1.z), __expf(8.f * vb1.w - rpot - 0.5f * vc1.w));
    pb[4] = pk2(__expf(8.f * vb2.x - rpot - 0.5f * vc2.x), __expf(8.f * vb2.y - rpot - 0.5f * vc2.y));
    pb[5] = pk2(__expf(8.f * vb2.z - rpot - 0.5f * vc2.z), __expf(8.f * vb2.w - rpot - 0.5f * vc2.w));
    pb[6] = pk2(__expf(8.f * vb3.x - rpot - 0.5f * vc3.x), __expf(8.f * vb3.y - rpot - 0.5f * vc3.y));
    pb[7] = pk2(__expf(8.f * vb3.z - rpot - 0.5f * vc3.z), __expf(8.f * vb3.w - rpot - 0.5f * vc3.w));
    float4 va0 = *(const float4*)(Xrow + k0);
    float4 va1 = *(const float4*)(Xrow + k0 + 4);
    float4 va2 = *(const float4*)(Xrow + k0 + 8);
    float4 va3 = *(const float4*)(Xrow + k0 + 12);
    unsigned int pa[8];
    pa[0] = pk2(va0.x, va0.y); pa[1] = pk2(va0.z, va0.w);
    pa[2] = pk2(va1.x, va1.y); pa[3] = pk2(va1.z, va1.w);
    pa[4] = pk2(va2.x, va2.y); pa[5] = pk2(va2.z, va2.w);
    pa[6] = pk2(va3.x, va3.y); pa[7] = pk2(va3.z, va3.w);

    *(uint4*)(Bs + sr * 32 + sk)     = *(uint4*)(pb);
    *(uint4*)(Bs + sr * 32 + sk + 8) = *(uint4*)(pb + 4);
    *(uint4*)(As + sr * 32 + sk)     = *(uint4*)(pa);
    *(uint4*)(As + sr * 32 + sk + 8) = *(uint4*)(pa + 4);

    __syncthreads();

    const int kq2 = (lane >> 4) * 8;
    const int fr2 = lane & 15;
    short8 af[4], bf[4];
    #pragma unroll
    for (int t = 0; t < 4; ++t)
      af[t] = *(const short8*)(As + (wm * 64 + t * 16 + fr2) * 32 + kq2);
    #pragma unroll
    for (int t = 0; t < 4; ++t)
      bf[t] = *(const short8*)(Bs + (wn * 64 + t * 16 + fr2) * 32 + kq2);
    #pragma unroll
    for (int mt = 0; mt < 4; ++mt)
      #pragma unroll
      for (int nt = 0; nt < 4; ++nt)
        acc[mt][nt] = __builtin_amdgcn_mfma_f32_16x16x32_bf16(af[mt], bf[nt], acc[mt][nt], 0, 0, 0);

    __syncthreads();
  }

  const int crow0 = m0 + wm * 64 + (lane >> 4) * 4;
  const int ccol0 = n0 + wn * 64 + (lane & 15);
  #pragma unroll
  for (int mt = 0; mt < 4; ++mt)
    #pragma unroll
    for (int nt = 0; nt < 4; ++nt)
      #pragma unroll
      for (int r = 0; r < 4; ++r)
        out[(size_t)(crow0 + mt * 16 + r) * 1024 + ccol0 + nt * 16] = acc[mt][nt][r];
}

extern "C" void kernel_launch(void* const* d_in, const int* in_sizes, int n_in,
                              void* d_out, int out_size, void* d_ws, size_t ws_size,
                              hipStream_t stream) {
  const float* x = (const float*)d_in[0];        // [8,4096,1024] fp32
  const float* weight = (const float*)d_in[1];   // [1024,1024] fp32
  float* out = (float*)d_out;                    // [8,4096,1024] fp32

  // ws: R0,C0,R1,C1 (16 KB) [+ optional Wb bf16 2 MB if ws_size permits]
  float* R0 = (float*)d_ws;
  float* C0 = R0 + 1024;
  float* R1 = C0 + 1024;
  float* C1 = R1 + 1024;
  unsigned short* Wb = (unsigned short*)(C1 + 1024);
  const size_t need_a = 16 * 1024 + 2 * 1024 * 1024;

  for (int t = 0; t < 10; ++t) {
    const float *Ri, *Ci;
    float *Ro, *Co;
    if ((t & 1) == 0) { Ri = R0; Ci = C0; Ro = R1; Co = C1; }
    else              { Ri = R1; Ci = C1; Ro = R0; Co = C0; }
    sinkhorn_step<<<1088, 256, 0, stream>>>(weight, Ri, Ci, Ro, Co, (t == 0) ? 1 : 0);
  }
  // after t=9 (odd), final potentials in R0/C0

  if (ws_size >= need_a) {
    make_w<<<1024, 256, 0, stream>>>(weight, R0, C0, Wb);
    gemm_a<<<2048, 256, 0, stream>>>(x, Wb, out);
  } else {
    gemm_b<<<2048, 256, 0, stream>>>(x, weight, R0, C0, out);
  }
}

// Round 5
// 377.496 us; speedup vs baseline: 1.4681x; 1.1198x over previous
//
#include <hip/hip_runtime.h>
#include <hip/hip_bf16.h>

// ---------------------------------------------------------------------------
// SinkhornLinear: W = sinkhorn(weight) [1024x1024], out = x @ W^T
// x: [8,4096,1024] fp32 -> M=32768, K=1024, N=1024, out fp32.
//
// Session facts (measured):
//   - grid-wide sync ~20us regardless of mechanism (cg 108us, atomic 21us,
//     dependent dispatch ~19-21us) -> Sinkhorn = 10 serial dispatches, floor
//     set by dispatch overhead, not device work.
//   - R9 GEMM: XOR(r&7) swizzle at BK=64 -> SQ_LDS_BANK_CONFLICT == 0
//     (verified), but dbuf(48KB LDS)+vx-prefetch(128 VGPR)+lgkmcnt-drain
//     pipeline dropped occupancy 37->22% and regressed 175->224us.
//
// R10: (a) GEMM single-buffered BK=64 conflict-free, 32KB LDS, no manual
//      pipeline; two variants: gemm_bb (A,B both global_load_lds; needs
//      bf16 X) and gemm_f (fp32-A cvt staging). (b) X->bf16 pre-convert
//      folded into sinkhorn step 1 when ws >= 66MB. (c) Sinkhorn grid
//      1088->320 (launch-floor scaling test).
// ---------------------------------------------------------------------------

typedef __attribute__((ext_vector_type(8))) short short8;   // 8 bf16 = 4 VGPRs
typedef __attribute__((ext_vector_type(4))) float f32x4;

// packed fp32x2 -> bf16x2 (hardware cvt_pk, round-to-nearest-even)
__device__ inline unsigned int pk2(float a, float b) {
  __hip_bfloat162 h = __float22bfloat162_rn(make_float2(a, b));
  union { __hip_bfloat162 h; unsigned int u; } cv;
  cv.h = h;
  return cv.u;
}

// One Sinkhorn iteration.
// Blocks 0..255:   row lse, 4 rows/block (1 row per wave).
// Blocks 256..319: col lse, 16 cols/block (R9 structure, verified).
// Blocks 320..2367 (step-1 only, big-ws): X fp32 -> bf16 convert.
__global__ void sinkhorn_step(const float* __restrict__ w,
                              const float* __restrict__ Rin,
                              const float* __restrict__ Cin,
                              float* __restrict__ Rout,
                              float* __restrict__ Cout,
                              int first,
                              const float* __restrict__ X,
                              unsigned short* __restrict__ Xb,
                              int do_cvt) {
  __shared__ float4 red4[256];
  const int tid = threadIdx.x;
  const int b = blockIdx.x;
  const int lane = tid & 63, wv = tid >> 6;
  if (b < 256) {
    // --- row part: wave wv owns row 4b+wv; lane covers 16 cols ---
    const int row = 4 * b + wv;
    const float* rp = w + (size_t)row * 1024 + lane * 16;
    float s = 0.f;
    #pragma unroll
    for (int q = 0; q < 4; ++q) {
      float4 v4 = *(const float4*)(rp + q * 4);
      float4 c4 = make_float4(0.f, 0.f, 0.f, 0.f);
      if (!first) c4 = *(const float4*)(Cin + lane * 16 + q * 4);
      s += __expf(8.f * v4.x - 0.5f * c4.x) + __expf(8.f * v4.y - 0.5f * c4.y)
         + __expf(8.f * v4.z - 0.5f * c4.z) + __expf(8.f * v4.w - 0.5f * c4.w);
    }
    #pragma unroll
    for (int off = 32; off > 0; off >>= 1) s += __shfl_down(s, off);
    if (lane == 0)
      Rout[row] = (first ? 0.f : 0.5f * Rin[row]) + __logf(s);
  } else if (b < 320) {
    // --- col part: 16 cols/block, coalesced float4 row segments ---
    const int cb = b - 256;
    const int c0 = cb * 16;
    const int rowg = tid >> 2, cg = tid & 3;
    const float* wp = w + (size_t)rowg * 1024 + c0 + cg * 4;
    float ax = 0.f, ay = 0.f, az = 0.f, aw = 0.f;
    #pragma unroll 4
    for (int p = 0; p < 16; ++p) {
      float4 wv4 = *(const float4*)(wp + (size_t)p * 64 * 1024);
      float rp = first ? 0.f : Rin[rowg + p * 64];
      float h = 0.5f * rp;
      ax += __expf(8.f * wv4.x - h);
      ay += __expf(8.f * wv4.y - h);
      az += __expf(8.f * wv4.z - h);
      aw += __expf(8.f * wv4.w - h);
    }
    red4[tid] = make_float4(ax, ay, az, aw);
    __syncthreads();
    if (tid < 16) {
      const int g = tid >> 2, e = tid & 3;
      float s = 0.f;
      #pragma unroll 8
      for (int q = 0; q < 64; ++q)
        s += ((const float*)&red4[q * 4 + g])[e];
      const int col = c0 + tid;
      Cout[col] = (first ? 0.f : 0.5f * Cin[col]) + __logf(s);
    }
  } else if (do_cvt) {
    // --- xcvt: 2048 blocks convert 32M fp32 -> bf16, coalesced ---
    const size_t idx0 = (size_t)(b - 320) * 256 + tid;   // 0..524287
    #pragma unroll
    for (int it = 0; it < 8; ++it) {
      size_t e = (it * 524288ull + idx0) * 8;
      float4 a = *(const float4*)(X + e);
      float4 c = *(const float4*)(X + e + 4);
      uint4 o;
      o.x = pk2(a.x, a.y); o.y = pk2(a.z, a.w);
      o.z = pk2(c.x, c.y); o.w = pk2(c.z, c.w);
      *(uint4*)(Xb + e) = o;
    }
  }
}

// W[i][j] = exp(8*w - 0.5*(R[i]+C[j])) -> bf16.
__global__ void make_w(const float* __restrict__ w, const float* __restrict__ R,
                       const float* __restrict__ C, unsigned short* __restrict__ Wb) {
  const int i = blockIdx.x;
  const int j = threadIdx.x * 4;
  const float r = 0.5f * R[i];
  float4 v = *(const float4*)(w + (size_t)i * 1024 + j);
  float4 cv = *(const float4*)(C + j);
  unsigned int o[2];
  o[0] = pk2(__expf(8.f * v.x - r - 0.5f * cv.x), __expf(8.f * v.y - r - 0.5f * cv.y));
  o[1] = pk2(__expf(8.f * v.z - r - 0.5f * cv.z), __expf(8.f * v.w - r - 0.5f * cv.w));
  *(uint2*)(Wb + (size_t)i * 1024 + j) = *(uint2*)o;
}

// XCD-group swizzle: id = h*64 + n*8 + c  ->  m-slab = c + 8h, n-slab = n.
__device__ inline void swizzle_mn(int id, int& m0, int& n0) {
  m0 = ((id & 7) + ((id >> 6) << 3)) << 7;
  n0 = ((id >> 3) & 7) << 7;
}

// ---------------------------------------------------------------------------
// gemm_bb: A,B both bf16 via global_load_lds w16, pre-swizzled sources.
// 128x128 tile, BK=64, single-buffered 32KB LDS, 2 barriers/K-step (m97
// structure). LDS slot (row, s) holds global chunk s^(row&7); read applies
// the same XOR -> conflict-free (verified 0 conflicts in R9).
// ---------------------------------------------------------------------------
__global__ __launch_bounds__(256) void gemm_bb(const unsigned short* __restrict__ Xb,
                                               const unsigned short* __restrict__ Wb,
                                               float* __restrict__ out) {
  __shared__ unsigned short As[128 * 64];
  __shared__ unsigned short Bs[128 * 64];
  const int tid = threadIdx.x;
  const int lane = tid & 63, wave = tid >> 6;
  const int wm = wave >> 1, wn = wave & 1;
  int m0, n0;
  swizzle_mn(blockIdx.x, m0, n0);

  f32x4 acc[4][4] = {};
  const int fr = lane & 15, kq = lane >> 4;

  for (int t = 0; t < 16; ++t) {
    const int k0 = t * 64;
    #pragma unroll
    for (int is = 0; is < 4; ++is) {
      int idx = is * 256 + tid;
      int lrow = idx >> 3;
      int g = (idx & 7) ^ (lrow & 7);
      const unsigned short* ga = Xb + (size_t)(m0 + lrow) * 1024 + k0 + g * 8;
      const unsigned short* gb = Wb + (size_t)(n0 + lrow) * 1024 + k0 + g * 8;
      unsigned short* la = As + (size_t)(is * 256 + wave * 64) * 8;
      unsigned short* lb = Bs + (size_t)(is * 256 + wave * 64) * 8;
      __builtin_amdgcn_global_load_lds(
          (const __attribute__((address_space(1))) unsigned int*)ga,
          (__attribute__((address_space(3))) unsigned int*)la, 16, 0, 0);
      __builtin_amdgcn_global_load_lds(
          (const __attribute__((address_space(1))) unsigned int*)gb,
          (__attribute__((address_space(3))) unsigned int*)lb, 16, 0, 0);
    }
    __syncthreads();   // compiler drains vmcnt before barrier

    #pragma unroll
    for (int kk = 0; kk < 2; ++kk) {
      short8 af[4], bf[4];
      #pragma unroll
      for (int mt = 0; mt < 4; ++mt) {
        int row = wm * 64 + mt * 16 + fr;
        int cp = (kk * 4 + kq) ^ (row & 7);
        af[mt] = *(const short8*)(As + (size_t)row * 64 + cp * 8);
      }
      #pragma unroll
      for (int nt = 0; nt < 4; ++nt) {
        int row = wn * 64 + nt * 16 + fr;
        int cp = (kk * 4 + kq) ^ (row & 7);
        bf[nt] = *(const short8*)(Bs + (size_t)row * 64 + cp * 8);
      }
      #pragma unroll
      for (int mt = 0; mt < 4; ++mt)
        #pragma unroll
        for (int nt = 0; nt < 4; ++nt)
          acc[mt][nt] = __builtin_amdgcn_mfma_f32_16x16x32_bf16(af[mt], bf[nt], acc[mt][nt], 0, 0, 0);
    }
    __syncthreads();
  }

  const int crow0 = m0 + wm * 64 + (lane >> 4) * 4;
  const int ccol0 = n0 + wn * 64 + fr;
  #pragma unroll
  for (int mt = 0; mt < 4; ++mt)
    #pragma unroll
    for (int nt = 0; nt < 4; ++nt)
      #pragma unroll
      for (int r = 0; r < 4; ++r)
        out[(size_t)(crow0 + mt * 16 + r) * 1024 + ccol0 + nt * 16] = acc[mt][nt][r];
}

// ---------------------------------------------------------------------------
// gemm_f: A fp32 -> cvt -> swizzled ds_write; B via global_load_lds
// pre-swizzled. Same 128x128/BK=64 conflict-free layout, single-buffered.
// ---------------------------------------------------------------------------
__global__ __launch_bounds__(256) void gemm_f(const float* __restrict__ X,
                                              const unsigned short* __restrict__ Wb,
                                              float* __restrict__ out) {
  __shared__ unsigned short As[128 * 64];
  __shared__ unsigned short Bs[128 * 64];
  const int tid = threadIdx.x;
  const int lane = tid & 63, wave = tid >> 6;
  const int wm = wave >> 1, wn = wave & 1;
  int m0, n0;
  swizzle_mn(blockIdx.x, m0, n0);

  f32x4 acc[4][4] = {};
  const int ar = tid >> 1, ah = tid & 1;
  const float* Xrow = X + (size_t)(m0 + ar) * 1024 + ah * 32;
  const int fr = lane & 15, kq = lane >> 4;

  for (int t = 0; t < 16; ++t) {
    const int k0 = t * 64;
    #pragma unroll
    for (int is = 0; is < 4; ++is) {
      int idx = is * 256 + tid;
      int lrow = idx >> 3;
      int g = (idx & 7) ^ (lrow & 7);
      const unsigned short* gb = Wb + (size_t)(n0 + lrow) * 1024 + k0 + g * 8;
      unsigned short* lb = Bs + (size_t)(is * 256 + wave * 64) * 8;
      __builtin_amdgcn_global_load_lds(
          (const __attribute__((address_space(1))) unsigned int*)gb,
          (__attribute__((address_space(3))) unsigned int*)lb, 16, 0, 0);
    }
    // A: 32 fp32 -> 16 cvt_pk -> 4 swizzled ds_write_b128 (transient regs)
    #pragma unroll
    for (int q = 0; q < 4; ++q) {
      float4 a = *(const float4*)(Xrow + k0 + q * 8);
      float4 c = *(const float4*)(Xrow + k0 + q * 8 + 4);
      uint4 o;
      o.x = pk2(a.x, a.y); o.y = pk2(a.z, a.w);
      o.z = pk2(c.x, c.y); o.w = pk2(c.z, c.w);
      int cp = (ah * 4 + q) ^ (ar & 7);
      *(uint4*)(As + (size_t)ar * 64 + cp * 8) = o;
    }
    __syncthreads();

    #pragma unroll
    for (int kk = 0; kk < 2; ++kk) {
      short8 af[4], bf[4];
      #pragma unroll
      for (int mt = 0; mt < 4; ++mt) {
        int row = wm * 64 + mt * 16 + fr;
        int cp = (kk * 4 + kq) ^ (row & 7);
        af[mt] = *(const short8*)(As + (size_t)row * 64 + cp * 8);
      }
      #pragma unroll
      for (int nt = 0; nt < 4; ++nt) {
        int row = wn * 64 + nt * 16 + fr;
        int cp = (kk * 4 + kq) ^ (row & 7);
        bf[nt] = *(const short8*)(Bs + (size_t)row * 64 + cp * 8);
      }
      #pragma unroll
      for (int mt = 0; mt < 4; ++mt)
        #pragma unroll
        for (int nt = 0; nt < 4; ++nt)
          acc[mt][nt] = __builtin_amdgcn_mfma_f32_16x16x32_bf16(af[mt], bf[nt], acc[mt][nt], 0, 0, 0);
    }
    __syncthreads();
  }

  const int crow0 = m0 + wm * 64 + (lane >> 4) * 4;
  const int ccol0 = n0 + wn * 64 + fr;
  #pragma unroll
  for (int mt = 0; mt < 4; ++mt)
    #pragma unroll
    for (int nt = 0; nt < 4; ++nt)
      #pragma unroll
      for (int r = 0; r < 4; ++r)
        out[(size_t)(crow0 + mt * 16 + r) * 1024 + ccol0 + nt * 16] = acc[mt][nt][r];
}

// ---------------------------------------------------------------------------
// gemm_b (tiny-ws fallback): W recomputed in B-staging (verified structure).
// ---------------------------------------------------------------------------
__global__ __launch_bounds__(256) void gemm_b(const float* __restrict__ X,
                                              const float* __restrict__ w,
                                              const float* __restrict__ R,
                                              const float* __restrict__ C,
                                              float* __restrict__ out) {
  __shared__ unsigned short As[128 * 32];
  __shared__ unsigned short Bs[128 * 32];
  const int tid = threadIdx.x;
  const int lane = tid & 63, wave = tid >> 6;
  const int wm = wave >> 1, wn = wave & 1;
  int m0, n0;
  swizzle_mn(blockIdx.x, m0, n0);

  f32x4 acc[4][4] = {};
  const int sr = tid >> 1, sk = (tid & 1) * 16;
  const float* Xrow = X + (size_t)(m0 + sr) * 1024 + sk;
  const float* Wrow = w + (size_t)(n0 + sr) * 1024 + sk;
  const float rpot = 0.5f * R[n0 + sr];

  for (int k0 = 0; k0 < 1024; k0 += 32) {
    float4 vb0 = *(const float4*)(Wrow + k0);
    float4 vb1 = *(const float4*)(Wrow + k0 + 4);
    float4 vb2 = *(const float4*)(Wrow + k0 + 8);
    float4 vb3 = *(const float4*)(Wrow + k0 + 12);
    float4 vc0 = *(const float4*)(C + k0 + sk);
    float4 vc1 = *(const float4*)(C + k0 + sk + 4);
    float4 vc2 = *(const float4*)(C + k0 + sk + 8);
    float4 vc3 = *(const float4*)(C + k0 + sk + 12);
    unsigned int pb[8];
    pb[0] = pk2(__expf(8.f * vb0.x - rpot - 0.5f * vc0.x), __expf(8.f * vb0.y - rpot - 0.5f * vc0.y));
    pb[1] = pk2(__expf(8.f * vb0.z - rpot - 0.5f * vc0.z), __expf(8.f * vb0.w - rpot - 0.5f * vc0.w));
    pb[2] = pk2(__expf(8.f * vb1.x - rpot - 0.5f * vc1.x), __expf(8.f * vb1.y - rpot - 0.5f * vc1.y));
    pb[3] = pk2(__expf(8.f * vb1.z - rpot - 0.5f * vc1.z), __expf(8.f * vb1.w - rpot - 0.5f * vc1.w));
    pb[4] = pk2(__expf(8.f * vb2.x - rpot - 0.5f * vc2.x), __expf(8.f * vb2.y - rpot - 0.5f * vc2.y));
    pb[5] = pk2(__expf(8.f * vb2.z - rpot - 0.5f * vc2.z), __expf(8.f * vb2.w - rpot - 0.5f * vc2.w));
    pb[6] = pk2(__expf(8.f * vb3.x - rpot - 0.5f * vc3.x), __expf(8.f * vb3.y - rpot - 0.5f * vc3.y));
    pb[7] = pk2(__expf(8.f * vb3.z - rpot - 0.5f * vc3.z), __expf(8.f * vb3.w - rpot - 0.5f * vc3.w));
    float4 va0 = *(const float4*)(Xrow + k0);
    float4 va1 = *(const float4*)(Xrow + k0 + 4);
    float4 va2 = *(const float4*)(Xrow + k0 + 8);
    float4 va3 = *(const float4*)(Xrow + k0 + 12);
    unsigned int pa[8];
    pa[0] = pk2(va0.x, va0.y); pa[1] = pk2(va0.z, va0.w);
    pa[2] = pk2(va1.x, va1.y); pa[3] = pk2(va1.z, va1.w);
    pa[4] = pk2(va2.x, va2.y); pa[5] = pk2(va2.z, va2.w);
    pa[6] = pk2(va3.x, va3.y); pa[7] = pk2(va3.z, va3.w);

    *(uint4*)(Bs + sr * 32 + sk)     = *(uint4*)(pb);
    *(uint4*)(Bs + sr * 32 + sk + 8) = *(uint4*)(pb + 4);
    *(uint4*)(As + sr * 32 + sk)     = *(uint4*)(pa);
    *(uint4*)(As + sr * 32 + sk + 8) = *(uint4*)(pa + 4);

    __syncthreads();

    const int kq2 = (lane >> 4) * 8;
    const int fr2 = lane & 15;
    short8 af[4], bf[4];
    #pragma unroll
    for (int t = 0; t < 4; ++t)
      af[t] = *(const short8*)(As + (wm * 64 + t * 16 + fr2) * 32 + kq2);
    #pragma unroll
    for (int t = 0; t < 4; ++t)
      bf[t] = *(const short8*)(Bs + (wn * 64 + t * 16 + fr2) * 32 + kq2);
    #pragma unroll
    for (int mt = 0; mt < 4; ++mt)
      #pragma unroll
      for (int nt = 0; nt < 4; ++nt)
        acc[mt][nt] = __builtin_amdgcn_mfma_f32_16x16x32_bf16(af[mt], bf[nt], acc[mt][nt], 0, 0, 0);

    __syncthreads();
  }

  const int crow0 = m0 + wm * 64 + (lane >> 4) * 4;
  const int ccol0 = n0 + wn * 64 + (lane & 15);
  #pragma unroll
  for (int mt = 0; mt < 4; ++mt)
    #pragma unroll
    for (int nt = 0; nt < 4; ++nt)
      #pragma unroll
      for (int r = 0; r < 4; ++r)
        out[(size_t)(crow0 + mt * 16 + r) * 1024 + ccol0 + nt * 16] = acc[mt][nt][r];
}

extern "C" void kernel_launch(void* const* d_in, const int* in_sizes, int n_in,
                              void* d_out, int out_size, void* d_ws, size_t ws_size,
                              hipStream_t stream) {
  const float* x = (const float*)d_in[0];        // [8,4096,1024] fp32
  const float* weight = (const float*)d_in[1];   // [1024,1024] fp32
  float* out = (float*)d_out;                    // [8,4096,1024] fp32

  // ws: R0,C0,R1,C1 (16KB) | Wb bf16 (2MB) | Xb bf16 (64MB)
  float* R0 = (float*)d_ws;
  float* C0 = R0 + 1024;
  float* R1 = C0 + 1024;
  float* C1 = R1 + 1024;
  unsigned short* Wb = (unsigned short*)(C1 + 1024);
  unsigned short* Xb = Wb + (size_t)1024 * 1024;
  const size_t need_small = 16 * 1024 + 2 * 1024 * 1024;
  const size_t need_big = need_small + (size_t)32768 * 1024 * 2;
  const int big = (ws_size >= need_big) ? 1 : 0;
  const int small_ok = (ws_size >= need_small) ? 1 : 0;

  for (int t = 0; t < 10; ++t) {
    const float *Ri, *Ci;
    float *Ro, *Co;
    if ((t & 1) == 0) { Ri = R0; Ci = C0; Ro = R1; Co = C1; }
    else              { Ri = R1; Ci = C1; Ro = R0; Co = C0; }
    const int cvt = (t == 0 && big) ? 1 : 0;
    const int grid = cvt ? 2368 : 320;
    sinkhorn_step<<<grid, 256, 0, stream>>>(weight, Ri, Ci, Ro, Co,
                                            (t == 0) ? 1 : 0, x, Xb, cvt);
  }
  // after t=9 (odd), final potentials in R0/C0

  if (small_ok) {
    make_w<<<1024, 256, 0, stream>>>(weight, R0, C0, Wb);
    if (big) gemm_bb<<<2048, 256, 0, stream>>>(Xb, Wb, out);
    else     gemm_f<<<2048, 256, 0, stream>>>(x, Wb, out);
  } else {
    gemm_b<<<2048, 256, 0, stream>>>(x, weight, R0, C0, out);
  }
}